// Round 5
// baseline (145.732 us; speedup 1.0000x reference)
//
#include <hip/hip_runtime.h>
#include <hip/hip_bf16.h>

typedef __attribute__((ext_vector_type(8))) short short8;
typedef __attribute__((ext_vector_type(4))) float floatx4;

__device__ __forceinline__ unsigned short f2bf(float x) {
    union { float f; unsigned u; } v; v.f = x;
    unsigned r = v.u + 0x7fffu + ((v.u >> 16) & 1u);   // RNE; inputs here are never NaN
    return (unsigned short)(r >> 16);
}

__device__ __forceinline__ short8 pack8(float4 a, float4 b) {
    short8 s;
    s[0] = (short)f2bf(a.x); s[1] = (short)f2bf(a.y);
    s[2] = (short)f2bf(a.z); s[3] = (short)f2bf(a.w);
    s[4] = (short)f2bf(b.x); s[5] = (short)f2bf(b.y);
    s[6] = (short)f2bf(b.z); s[7] = (short)f2bf(b.w);
    return s;
}

__device__ __forceinline__ float fast_tanh(float x) {
    // tanh(x) = 1 - 2/(e^{2x}+1); exact saturation at +-inf (rcp(inf)=0)
    float e = __expf(2.0f * x);
    return 1.0f - 2.0f * __builtin_amdgcn_rcpf(e + 1.0f);
}

// ---------------------------------------------------------------------------
// Projection as MFMA GEMM; output in PRE-FRAGMENTED TILE LAYOUT:
//   frag[b][stile=s/16][kchunk=ch/32][lane][8shorts], ch = h*64+e.
// (unchanged from round 4 — ~10 us, near its 8 us HBM floor)
// ---------------------------------------------------------------------------
__global__ __launch_bounds__(256) void proj_kernel(
    const float* __restrict__ qin, const float* __restrict__ kin,
    const float* __restrict__ Wq, const float* __restrict__ bq,
    const float* __restrict__ Wk, const float* __restrict__ bk,
    const float* __restrict__ Wc,
    unsigned short* __restrict__ qt, unsigned short* __restrict__ kt)
{
    __shared__ unsigned short scr[4][16 * 72];
    const int which = blockIdx.y;             // 0 = q, 1 = k
    const float* in  = which ? kin : qin;
    const float* W   = which ? Wk  : Wq;
    const float* bi  = which ? bk  : bq;
    unsigned short* out = which ? kt : qt;

    const int tid  = threadIdx.x;
    const int lane = tid & 63;
    const int w    = tid >> 6;
    const int ln   = lane & 15;
    const int g    = lane >> 4;

    short8 wf[4][2];
    #pragma unroll
    for (int c = 0; c < 4; ++c)
        #pragma unroll
        for (int t = 0; t < 2; ++t) {
            const float* p = W + (c * 16 + ln) * 64 + t * 32 + (g << 3);
            wf[c][t] = pack8(*(const float4*)p, *(const float4*)(p + 4));
        }
    float be[4];
    #pragma unroll
    for (int c = 0; c < 4; ++c) be[c] = bi[c * 16 + ln];

    const int rb = blockIdx.x << 6;           // block's 64 rows: same (b,h)
    const int b  = rb >> 14;
    const int h  = (rb >> 10) & 15;
    const float sc = which ? 1.0f : Wc[h];

    const int r0 = rb + (w << 4);             // this wave's 16 rows (one s-tile)
    const int s0 = (rb & 1023) + (w << 4);
    floatx4 acc[4] = {{0,0,0,0},{0,0,0,0},{0,0,0,0},{0,0,0,0}};
    #pragma unroll
    for (int t = 0; t < 2; ++t) {
        const float* p = in + (r0 + ln) * 64 + t * 32 + (g << 3);
        short8 af = pack8(*(const float4*)p, *(const float4*)(p + 4));
        #pragma unroll
        for (int c = 0; c < 4; ++c)
            acc[c] = __builtin_amdgcn_mfma_f32_16x16x32_bf16(af, wf[c][t], acc[c], 0, 0, 0);
    }

    // C/D: col e = c*16+ln, row m = g*4+r.  Stage tile (16 s x 64 e) in LDS.
    unsigned short* s_scr = scr[w];
    #pragma unroll
    for (int c = 0; c < 4; ++c)
        #pragma unroll
        for (int r = 0; r < 4; ++r)
            s_scr[((g << 2) + r) * 72 + (c << 4) + ln] =
                f2bf(fast_tanh(acc[c][r] + be[c]) * sc);
    __syncthreads();

    const int itg = (b << 6) + (s0 >> 4);
    unsigned short* obase = out + ((size_t)(itg * 32 + h * 2) << 9) + (lane << 3);
    #pragma unroll
    for (int e2 = 0; e2 < 2; ++e2) {          // kchunk = h*2 + e2
        short8 v = *(const short8*)&s_scr[ln * 72 + (e2 << 5) + (g << 3)];
        *(short8*)(obase + (e2 << 9)) = v;
    }
}

// ---------------------------------------------------------------------------
// Fused QK^T + mask + softmax. Block = 32 q-rows x 1024 k-cols, 16 waves;
// wave w: 2 s-tiles x 4 n-tiles (cols w*64..+63), 8 accumulators, so each
// kt byte read per block serves 2x the outputs of round 4 (L2 traffic
// 512->256 MB; attn was L2-BW-bound at ~60% of the 19.5 us floor).
// Grid 128: half the CUs, but L2 BW is per-XCD and all 8 XCDs stay loaded;
// MFMA work (3.4 us chip-wide) has 2x headroom on 128 CUs.
// All loads are contiguous 1 KB bursts (frag-tile layout). No max-sub
// softmax (|logit| small; masked -> exactly 0). bc cancels in softmax.
// b = blockIdx&3 -> each XCD serves one batch (kt 2 MB resident in 4 MB L2).
// ---------------------------------------------------------------------------
__global__ __launch_bounds__(1024, 4) void attn_kernel(
    const unsigned short* __restrict__ qt, const unsigned short* __restrict__ kt,
    const int* __restrict__ mask, float* __restrict__ out)
{
    __shared__ float red[16][32];
    const int tid  = threadIdx.x;
    const int lane = tid & 63;
    const int w    = tid >> 6;                // 0..15
    const int ln   = lane & 15;
    const int g    = lane >> 4;

    const int b   = blockIdx.x & 3;
    const int qb  = blockIdx.x >> 2;          // 0..31
    const int i0  = qb << 5;                  // 32-row q tile
    const int jw0 = w << 6;                   // wave's 64-col k range

    const unsigned short* aP = qt + ((size_t)((b << 6) + (qb << 1)) << 14) + (lane << 3);
    const unsigned short* bP = kt + ((size_t)((b << 6) + (w << 2)) << 14) + (lane << 3);

    floatx4 acc[2][4] = {{{0,0,0,0},{0,0,0,0},{0,0,0,0},{0,0,0,0}},
                         {{0,0,0,0},{0,0,0,0},{0,0,0,0},{0,0,0,0}}};

    // prime the pipeline (chunk stride = 512 shorts = 1 KB; tile stride 1<<14)
    short8 av0 = *(const short8*)(aP);
    short8 av1 = *(const short8*)(aP + (1 << 14));
    short8 bv0 = *(const short8*)(bP);
    short8 bv1 = *(const short8*)(bP + (1 << 14));
    short8 bv2 = *(const short8*)(bP + (2 << 14));
    short8 bv3 = *(const short8*)(bP + (3 << 14));

    for (int kc = 1; kc < 32; ++kc) {
        const int o = kc << 9;
        short8 an0 = *(const short8*)(aP + o);
        short8 an1 = *(const short8*)(aP + (1 << 14) + o);
        short8 bn0 = *(const short8*)(bP + o);
        short8 bn1 = *(const short8*)(bP + (1 << 14) + o);
        short8 bn2 = *(const short8*)(bP + (2 << 14) + o);
        short8 bn3 = *(const short8*)(bP + (3 << 14) + o);
        acc[0][0] = __builtin_amdgcn_mfma_f32_16x16x32_bf16(av0, bv0, acc[0][0], 0, 0, 0);
        acc[0][1] = __builtin_amdgcn_mfma_f32_16x16x32_bf16(av0, bv1, acc[0][1], 0, 0, 0);
        acc[0][2] = __builtin_amdgcn_mfma_f32_16x16x32_bf16(av0, bv2, acc[0][2], 0, 0, 0);
        acc[0][3] = __builtin_amdgcn_mfma_f32_16x16x32_bf16(av0, bv3, acc[0][3], 0, 0, 0);
        acc[1][0] = __builtin_amdgcn_mfma_f32_16x16x32_bf16(av1, bv0, acc[1][0], 0, 0, 0);
        acc[1][1] = __builtin_amdgcn_mfma_f32_16x16x32_bf16(av1, bv1, acc[1][1], 0, 0, 0);
        acc[1][2] = __builtin_amdgcn_mfma_f32_16x16x32_bf16(av1, bv2, acc[1][2], 0, 0, 0);
        acc[1][3] = __builtin_amdgcn_mfma_f32_16x16x32_bf16(av1, bv3, acc[1][3], 0, 0, 0);
        av0 = an0; av1 = an1; bv0 = bn0; bv1 = bn1; bv2 = bn2; bv3 = bn3;
    }
    acc[0][0] = __builtin_amdgcn_mfma_f32_16x16x32_bf16(av0, bv0, acc[0][0], 0, 0, 0);
    acc[0][1] = __builtin_amdgcn_mfma_f32_16x16x32_bf16(av0, bv1, acc[0][1], 0, 0, 0);
    acc[0][2] = __builtin_amdgcn_mfma_f32_16x16x32_bf16(av0, bv2, acc[0][2], 0, 0, 0);
    acc[0][3] = __builtin_amdgcn_mfma_f32_16x16x32_bf16(av0, bv3, acc[0][3], 0, 0, 0);
    acc[1][0] = __builtin_amdgcn_mfma_f32_16x16x32_bf16(av1, bv0, acc[1][0], 0, 0, 0);
    acc[1][1] = __builtin_amdgcn_mfma_f32_16x16x32_bf16(av1, bv1, acc[1][1], 0, 0, 0);
    acc[1][2] = __builtin_amdgcn_mfma_f32_16x16x32_bf16(av1, bv2, acc[1][2], 0, 0, 0);
    acc[1][3] = __builtin_amdgcn_mfma_f32_16x16x32_bf16(av1, bv3, acc[1][3], 0, 0, 0);

    // epilogue. C/D: col j = jw0 + nt*16 + ln, row i = i0 + t*16 + g*4 + r.
    int rowbase[2];
    #pragma unroll
    for (int t = 0; t < 2; ++t)
        rowbase[t] = ((b << 10) + i0 + (t << 4) + (g << 2)) << 10;

    int mv[2][4][4];                          // issue mask loads first (overlap exp)
    #pragma unroll
    for (int t = 0; t < 2; ++t)
        #pragma unroll
        for (int nt = 0; nt < 4; ++nt) {
            const int j = jw0 + (nt << 4) + ln;
            #pragma unroll
            for (int r = 0; r < 4; ++r)
                mv[t][nt][r] = mask[rowbase[t] + (r << 10) + j];
        }

    float psum[2][4] = {{0.f,0.f,0.f,0.f},{0.f,0.f,0.f,0.f}};
    #pragma unroll
    for (int t = 0; t < 2; ++t)
        #pragma unroll
        for (int nt = 0; nt < 4; ++nt)
            #pragma unroll
            for (int r = 0; r < 4; ++r) {
                float e = mv[t][nt][r] ? __expf(acc[t][nt][r]) : 0.0f;
                acc[t][nt][r] = e;
                psum[t][r] += e;
            }
    #pragma unroll
    for (int off = 1; off < 16; off <<= 1)
        #pragma unroll
        for (int t = 0; t < 2; ++t)
            #pragma unroll
            for (int r = 0; r < 4; ++r)
                psum[t][r] += __shfl_xor(psum[t][r], off);
    if (ln == 0) {
        #pragma unroll
        for (int t = 0; t < 2; ++t)
            #pragma unroll
            for (int r = 0; r < 4; ++r)
                red[w][(t << 4) + (g << 2) + r] = psum[t][r];
    }
    __syncthreads();
    float inv[2][4];
    #pragma unroll
    for (int t = 0; t < 2; ++t)
        #pragma unroll
        for (int r = 0; r < 4; ++r) {
            float s = 0.f;
            #pragma unroll
            for (int ww = 0; ww < 16; ++ww) s += red[ww][(t << 4) + (g << 2) + r];
            inv[t][r] = 1.0f / s;
        }
    #pragma unroll
    for (int t = 0; t < 2; ++t) {
        float* ob = out + rowbase[t];
        #pragma unroll
        for (int nt = 0; nt < 4; ++nt) {
            const int j = jw0 + (nt << 4) + ln;
            #pragma unroll
            for (int r = 0; r < 4; ++r)
                ob[(r << 10) + j] = acc[t][nt][r] * inv[t][r];
        }
    }
}

extern "C" void kernel_launch(void* const* d_in, const int* in_sizes, int n_in,
                              void* d_out, int out_size, void* d_ws, size_t ws_size,
                              hipStream_t stream)
{
    const float* query = (const float*)d_in[0];
    const float* key   = (const float*)d_in[1];
    const int*   mask  = (const int*)d_in[2];
    const float* Wq    = (const float*)d_in[3];
    const float* bq    = (const float*)d_in[4];
    const float* Wk    = (const float*)d_in[5];
    const float* bk    = (const float*)d_in[6];
    const float* Wc    = (const float*)d_in[7];
    // d_in[8] (bc) intentionally unused: constant shift cancels in softmax.

    float* out = (float*)d_out;
    unsigned short* qt = (unsigned short*)d_ws;                 // 8 MiB bf16 (frag layout)
    unsigned short* kt = qt + (size_t)4 * 1024 * 1024;          // 8 MiB bf16 (frag layout)

    proj_kernel<<<dim3(1024, 2), 256, 0, stream>>>(query, key, Wq, bq, Wk, bk, Wc, qt, kt);
    attn_kernel<<<128, 1024, 0, stream>>>(qt, kt, mask, out);
}

// Round 6
// 139.357 us; speedup vs baseline: 1.0457x; 1.0457x over previous
//
#include <hip/hip_runtime.h>
#include <hip/hip_bf16.h>

typedef __attribute__((ext_vector_type(8))) short short8;
typedef __attribute__((ext_vector_type(4))) float floatx4;

__device__ __forceinline__ unsigned short f2bf(float x) {
    union { float f; unsigned u; } v; v.f = x;
    unsigned r = v.u + 0x7fffu + ((v.u >> 16) & 1u);   // RNE; inputs here are never NaN
    return (unsigned short)(r >> 16);
}

__device__ __forceinline__ short8 pack8(float4 a, float4 b) {
    short8 s;
    s[0] = (short)f2bf(a.x); s[1] = (short)f2bf(a.y);
    s[2] = (short)f2bf(a.z); s[3] = (short)f2bf(a.w);
    s[4] = (short)f2bf(b.x); s[5] = (short)f2bf(b.y);
    s[6] = (short)f2bf(b.z); s[7] = (short)f2bf(b.w);
    return s;
}

__device__ __forceinline__ float fast_tanh(float x) {
    // tanh(x) = 1 - 2/(e^{2x}+1); exact saturation at +-inf (rcp(inf)=0)
    float e = __expf(2.0f * x);
    return 1.0f - 2.0f * __builtin_amdgcn_rcpf(e + 1.0f);
}

// ---------------------------------------------------------------------------
// Projection as MFMA GEMM; output in PRE-FRAGMENTED TILE LAYOUT:
//   frag[b][stile=s/16][kchunk=ch/32][lane][8shorts], ch = h*64+e.
// (unchanged since round 4 — ~10 us, near its ~8 us HBM floor)
// ---------------------------------------------------------------------------
__global__ __launch_bounds__(256) void proj_kernel(
    const float* __restrict__ qin, const float* __restrict__ kin,
    const float* __restrict__ Wq, const float* __restrict__ bq,
    const float* __restrict__ Wk, const float* __restrict__ bk,
    const float* __restrict__ Wc,
    unsigned short* __restrict__ qt, unsigned short* __restrict__ kt)
{
    __shared__ unsigned short scr[4][16 * 72];
    const int which = blockIdx.y;             // 0 = q, 1 = k
    const float* in  = which ? kin : qin;
    const float* W   = which ? Wk  : Wq;
    const float* bi  = which ? bk  : bq;
    unsigned short* out = which ? kt : qt;

    const int tid  = threadIdx.x;
    const int lane = tid & 63;
    const int w    = tid >> 6;
    const int ln   = lane & 15;
    const int g    = lane >> 4;

    short8 wf[4][2];
    #pragma unroll
    for (int c = 0; c < 4; ++c)
        #pragma unroll
        for (int t = 0; t < 2; ++t) {
            const float* p = W + (c * 16 + ln) * 64 + t * 32 + (g << 3);
            wf[c][t] = pack8(*(const float4*)p, *(const float4*)(p + 4));
        }
    float be[4];
    #pragma unroll
    for (int c = 0; c < 4; ++c) be[c] = bi[c * 16 + ln];

    const int rb = blockIdx.x << 6;           // block's 64 rows: same (b,h)
    const int b  = rb >> 14;
    const int h  = (rb >> 10) & 15;
    const float sc = which ? 1.0f : Wc[h];

    const int r0 = rb + (w << 4);             // this wave's 16 rows (one s-tile)
    const int s0 = (rb & 1023) + (w << 4);
    floatx4 acc[4] = {{0,0,0,0},{0,0,0,0},{0,0,0,0},{0,0,0,0}};
    #pragma unroll
    for (int t = 0; t < 2; ++t) {
        const float* p = in + (r0 + ln) * 64 + t * 32 + (g << 3);
        short8 af = pack8(*(const float4*)p, *(const float4*)(p + 4));
        #pragma unroll
        for (int c = 0; c < 4; ++c)
            acc[c] = __builtin_amdgcn_mfma_f32_16x16x32_bf16(af, wf[c][t], acc[c], 0, 0, 0);
    }

    // C/D: col e = c*16+ln, row m = g*4+r.  Stage tile (16 s x 64 e) in LDS.
    unsigned short* s_scr = scr[w];
    #pragma unroll
    for (int c = 0; c < 4; ++c)
        #pragma unroll
        for (int r = 0; r < 4; ++r)
            s_scr[((g << 2) + r) * 72 + (c << 4) + ln] =
                f2bf(fast_tanh(acc[c][r] + be[c]) * sc);
    __syncthreads();

    const int itg = (b << 6) + (s0 >> 4);
    unsigned short* obase = out + ((size_t)(itg * 32 + h * 2) << 9) + (lane << 3);
    #pragma unroll
    for (int e2 = 0; e2 < 2; ++e2) {          // kchunk = h*2 + e2
        short8 v = *(const short8*)&s_scr[ln * 72 + (e2 << 5) + (g << 3)];
        *(short8*)(obase + (e2 << 9)) = v;
    }
}

// ---------------------------------------------------------------------------
// Fused QK^T + mask + softmax. Round-4 structure (16 q-rows x full width,
// grid 256, 16 waves, wave = 4 n-tiles) — proven optimal for the per-CU
// VMEM-return-bound regime (B bytes/CU invariant under tile size; round 5's
// 32-row tile concentrated the same bytes on half the CUs and regressed).
// New this round: A-tile (32 KB) and mask tile (64 KB, rows padded to 1032
// ints to break the 4-way quarter-wave bank alias) are staged into LDS once
// per block. K-loop A-reads move to the DS pipe (parallel with VMEM's B
// stream, removing 480 KB/CU of return-bus traffic); epilogue mask reads hit
// LDS instead of a latency-exposed strided global tail.
// ---------------------------------------------------------------------------
__global__ __launch_bounds__(1024, 4) void attn_kernel(
    const unsigned short* __restrict__ qt, const unsigned short* __restrict__ kt,
    const int* __restrict__ mask, float* __restrict__ out)
{
    __shared__ __align__(16) unsigned short Al[16384];   // 32 KB A-tile, frag order
    __shared__ __align__(16) int Ml[16 * 1032];          // 66 KB mask tile, padded rows
    __shared__ float red[16][16];

    const int tid  = threadIdx.x;
    const int lane = tid & 63;
    const int w    = tid >> 6;                // 0..15
    const int ln   = lane & 15;
    const int g    = lane >> 4;

    const int b   = blockIdx.x & 3;
    const int qb  = blockIdx.x >> 2;          // 0..63
    const int i0  = qb << 4;                  // 16-row q tile
    const int jw0 = w << 6;                   // wave's 64-col k range

    // ---- stage A (linear copy: frag layout is already chunk-major) ----
    const unsigned short* aSrc = qt + ((size_t)((b << 6) + qb) << 14);
    #pragma unroll
    for (int rr = 0; rr < 2; ++rr) {
        const int idx = (rr << 10) + tid;     // 8-short chunk id
        *(short8*)&Al[idx << 3] = *(const short8*)(aSrc + (idx << 3));
    }
    // ---- stage mask (16 rows x 1024 ints -> padded stride 1032) ----
    const int* mSrc = mask + (((b << 10) + i0) << 10);
    #pragma unroll
    for (int rr = 0; rr < 4; ++rr) {
        const int idx = (rr << 10) + tid;     // int4 chunk id, 256 per row
        const int li  = idx >> 8;
        const int cj  = idx & 255;
        *(int4*)&Ml[li * 1032 + (cj << 2)] = *(const int4*)(mSrc + (idx << 2));
    }
    __syncthreads();

    const unsigned short* bP = kt + ((size_t)((b << 6) + (w << 2)) << 14) + (lane << 3);
    const unsigned short* aL = &Al[lane << 3];

    floatx4 acc[4] = {{0,0,0,0},{0,0,0,0},{0,0,0,0},{0,0,0,0}};

    // prime the pipeline (chunk stride = 512 shorts = 1 KB; n-tile stride 1<<14)
    short8 av  = *(const short8*)(aL);
    short8 bv0 = *(const short8*)(bP);
    short8 bv1 = *(const short8*)(bP + (1 << 14));
    short8 bv2 = *(const short8*)(bP + (2 << 14));
    short8 bv3 = *(const short8*)(bP + (3 << 14));

    for (int kc = 1; kc < 32; ++kc) {
        const int o = kc << 9;
        short8 avn = *(const short8*)(aL + o);            // ds_read_b128
        short8 bn0 = *(const short8*)(bP + o);
        short8 bn1 = *(const short8*)(bP + (1 << 14) + o);
        short8 bn2 = *(const short8*)(bP + (2 << 14) + o);
        short8 bn3 = *(const short8*)(bP + (3 << 14) + o);
        acc[0] = __builtin_amdgcn_mfma_f32_16x16x32_bf16(av, bv0, acc[0], 0, 0, 0);
        acc[1] = __builtin_amdgcn_mfma_f32_16x16x32_bf16(av, bv1, acc[1], 0, 0, 0);
        acc[2] = __builtin_amdgcn_mfma_f32_16x16x32_bf16(av, bv2, acc[2], 0, 0, 0);
        acc[3] = __builtin_amdgcn_mfma_f32_16x16x32_bf16(av, bv3, acc[3], 0, 0, 0);
        av = avn; bv0 = bn0; bv1 = bn1; bv2 = bn2; bv3 = bn3;
    }
    acc[0] = __builtin_amdgcn_mfma_f32_16x16x32_bf16(av, bv0, acc[0], 0, 0, 0);
    acc[1] = __builtin_amdgcn_mfma_f32_16x16x32_bf16(av, bv1, acc[1], 0, 0, 0);
    acc[2] = __builtin_amdgcn_mfma_f32_16x16x32_bf16(av, bv2, acc[2], 0, 0, 0);
    acc[3] = __builtin_amdgcn_mfma_f32_16x16x32_bf16(av, bv3, acc[3], 0, 0, 0);

    // epilogue: masked exp (no max-sub: |logit| small; masked -> exactly 0),
    // per-row sums, normalize, store.  C/D: col j = jw0+nt*16+ln, row g*4+r.
    float psum[4] = {0.f, 0.f, 0.f, 0.f};
    const int rowbase = ((b << 10) + i0 + (g << 2)) << 10;   // + (r<<10) + j
    #pragma unroll
    for (int nt = 0; nt < 4; ++nt) {
        const int j = jw0 + (nt << 4) + ln;
        #pragma unroll
        for (int r = 0; r < 4; ++r) {
            const int mv = Ml[((g << 2) + r) * 1032 + j];
            float e = mv ? __expf(acc[nt][r]) : 0.0f;
            acc[nt][r] = e;
            psum[r] += e;
        }
    }
    #pragma unroll
    for (int off = 1; off < 16; off <<= 1)
        #pragma unroll
        for (int r = 0; r < 4; ++r) psum[r] += __shfl_xor(psum[r], off);
    if (ln == 0) {
        #pragma unroll
        for (int r = 0; r < 4; ++r) red[w][(g << 2) + r] = psum[r];
    }
    __syncthreads();
    float inv[4];
    #pragma unroll
    for (int r = 0; r < 4; ++r) {
        float t = 0.f;
        #pragma unroll
        for (int ww = 0; ww < 16; ++ww) t += red[ww][(g << 2) + r];
        inv[r] = 1.0f / t;
    }
    float* ob = out + rowbase;
    #pragma unroll
    for (int nt = 0; nt < 4; ++nt) {
        const int j = jw0 + (nt << 4) + ln;
        #pragma unroll
        for (int r = 0; r < 4; ++r)
            ob[(r << 10) + j] = acc[nt][r] * inv[r];
    }
}

extern "C" void kernel_launch(void* const* d_in, const int* in_sizes, int n_in,
                              void* d_out, int out_size, void* d_ws, size_t ws_size,
                              hipStream_t stream)
{
    const float* query = (const float*)d_in[0];
    const float* key   = (const float*)d_in[1];
    const int*   mask  = (const int*)d_in[2];
    const float* Wq    = (const float*)d_in[3];
    const float* bq    = (const float*)d_in[4];
    const float* Wk    = (const float*)d_in[5];
    const float* bk    = (const float*)d_in[6];
    const float* Wc    = (const float*)d_in[7];
    // d_in[8] (bc) intentionally unused: constant shift cancels in softmax.

    float* out = (float*)d_out;
    unsigned short* qt = (unsigned short*)d_ws;                 // 8 MiB bf16 (frag layout)
    unsigned short* kt = qt + (size_t)4 * 1024 * 1024;          // 8 MiB bf16 (frag layout)

    proj_kernel<<<dim3(1024, 2), 256, 0, stream>>>(query, key, Wq, bq, Wk, bk, Wc, qt, kt);
    attn_kernel<<<256, 1024, 0, stream>>>(qt, kt, mask, out);
}